// Round 5
// baseline (142.073 us; speedup 1.0000x reference)
//
#include <hip/hip_runtime.h>
#include <hip/hip_cooperative_groups.h>
#include <math.h>

namespace cg = cooperative_groups;

// GroupNorm2dInteger fused single-pass: x is read from HBM exactly ONCE.
// 512 blocks x 512 threads (cooperative; __launch_bounds__(512,4) caps VGPR at 128,
// LDS = 72KB -> 2 blocks/CU co-resident on 256 CUs = 512 blocks).
// Each thread holds its 128 elems as 23 float4 in regs + 9 float4 in LDS.
// Phase A: accumulate f64 sum/sumsq, wave-shuffle reduce, per-wave partials to ws.
// grid.sync(). Phase B: every block redundantly finalizes its sample's 64 partials
// in a fixed order (bit-identical params), then normalizes from regs/LDS, NT stores.

#define NSAMP 64
#define SELEMS (128 * 64 * 64)          // 524288 per sample
#define BLOCKS 512
#define THREADS 512
#define BLK_PER_SAMP 8                  // blocks per sample
#define CHUNK4 (SELEMS / BLK_PER_SAMP / 4)  // 16384 float4 per block
#define LDS_ITERS 9                     // 9*512 float4 = 72 KB LDS
#define REG_ITERS 23                    // 23 float4 = 92 VGPRs
// LDS_ITERS + REG_ITERS == CHUNK4 / THREADS == 32

typedef float f32x4 __attribute__((ext_vector_type(4)));

struct QPair { float f, u; };

__device__ __forceinline__ QPair quant1(float v, float mu, float is) {
    float d = (v - mu) * is;
    float t = floorf(d * 16.0f);
    t = fminf(fmaxf(t, -128.0f), 127.0f);
    QPair q;
    q.f = t * 0.0625f;
    q.u = (float)(((int)t) & 255);
    return q;
}

__device__ __forceinline__ void quant4(f32x4 v, float mu, float is,
                                       f32x4* rf, f32x4* ru) {
    QPair a = quant1(v.x, mu, is);
    QPair b = quant1(v.y, mu, is);
    QPair c = quant1(v.z, mu, is);
    QPair d = quant1(v.w, mu, is);
    f32x4 f, u;
    f.x = a.f; f.y = b.f; f.z = c.f; f.w = d.f;
    u.x = a.u; u.y = b.u; u.z = c.u; u.w = d.u;
    *rf = f; *ru = u;
}

// Fixed-order finalize: identical inputs + identical order -> bit-identical result
// in every block of a sample. Integer isqrt is exact.
__device__ __forceinline__ void compute_params(const double* __restrict__ part,
                                               const int* __restrict__ lut,
                                               int samp, int nper,
                                               float* mu_out, float* is_out) {
    double sum = 0.0, sum2 = 0.0;
    int jb = samp * nper;
    for (int j = 0; j < nper; ++j) {
        sum  += part[(jb + j) * 2];
        sum2 += part[(jb + j) * 2 + 1];
    }
    const double invN = 1.0 / (double)SELEMS;
    double mean = sum * invN;
    double mi = floor(mean * 16.0);                 // integer_floor_quantizer(mu,8,4)
    mi = fmin(fmax(mi, -128.0), 127.0);
    double mu = mi / 16.0;
    double var = sum2 * invN - 2.0 * mu * mean + mu * mu;
    if (var < 0.0) var = 0.0;
    double vq = floor(var * 256.0);                 // integer_floor_quantizer(var,16,8)
    vq = fmin(fmax(vq, -32768.0), 32767.0);
    int var_int = (int)vq;

    int res;
    if (var_int <= 0) {
        res = 65535;
    } else {
        int msb = 31 - __clz(var_int);      // <= 14
        int x_red = var_int << (15 - msb);  // MSB at bit 15
        int idx = (x_red >> 10) & 31;       // top 5 frac bits
        int lv = lut[idx];
        int e = 24 - msb;                   // in [10, 24]
        int e2 = e >> 1;
        if (e & 1) lv = (lv * 46340) >> 15; // SQRT2_FIX
        res = lv >> (15 - e2);              // shift in [3,10], never negative
        if (res > 65535) res = 65535;
    }
    if (res > 32767) res = 32767;           // quantize(res/256,16,8) clip

    *mu_out = (float)mu;
    *is_out = (float)res * (1.0f / 256.0f);
}

__global__ __launch_bounds__(THREADS, 4)
void gn_fused(const float* __restrict__ x, double* __restrict__ part,
              const int* __restrict__ lut,
              float* __restrict__ outf, float* __restrict__ outu) {
    int blk  = blockIdx.x;
    int samp = blk >> 3;
    int sub  = blk & 7;
    int t    = threadIdx.x;
    size_t base4 = (size_t)samp * (SELEMS / 4) + (size_t)sub * CHUNK4;
    const f32x4* xs = reinterpret_cast<const f32x4*>(x) + base4;

    __shared__ f32x4 lds4[LDS_ITERS * THREADS];   // 72 KB
    __shared__ float psh[2];

    f32x4 r[REG_ITERS];
    double s = 0.0, s2 = 0.0;

    #pragma unroll
    for (int i = 0; i < LDS_ITERS; ++i) {
        f32x4 v = xs[i * THREADS + t];
        lds4[i * THREADS + t] = v;
        double a = v.x, b = v.y, c = v.z, d = v.w;
        s  += (a + b) + (c + d);
        s2 += (a * a + b * b) + (c * c + d * d);
    }
    #pragma unroll
    for (int i = 0; i < REG_ITERS; ++i) {
        f32x4 v = xs[(LDS_ITERS + i) * THREADS + t];
        r[i] = v;
        double a = v.x, b = v.y, c = v.z, d = v.w;
        s  += (a + b) + (c + d);
        s2 += (a * a + b * b) + (c * c + d * d);
    }

    // wave (64-lane) shuffle reduction, deterministic
    #pragma unroll
    for (int off = 32; off > 0; off >>= 1) {
        s  += __shfl_down(s,  off, 64);
        s2 += __shfl_down(s2, off, 64);
    }
    int wid = t >> 6, lane = t & 63;
    if (lane == 0) {
        part[(blk * 8 + wid) * 2]     = s;
        part[(blk * 8 + wid) * 2 + 1] = s2;
    }

    cg::this_grid().sync();

    if (t == 0) {
        float mu, is;
        compute_params(part, lut, samp, 64, &mu, &is);
        psh[0] = mu; psh[1] = is;
    }
    __syncthreads();
    float mu = psh[0], is = psh[1];

    f32x4* of = reinterpret_cast<f32x4*>(outf) + base4;
    f32x4* ou = reinterpret_cast<f32x4*>(outu) + base4;

    #pragma unroll
    for (int i = 0; i < LDS_ITERS; ++i) {
        f32x4 v = lds4[i * THREADS + t];
        f32x4 rf, ru;
        quant4(v, mu, is, &rf, &ru);
        __builtin_nontemporal_store(rf, of + i * THREADS + t);
        __builtin_nontemporal_store(ru, ou + i * THREADS + t);
    }
    #pragma unroll
    for (int i = 0; i < REG_ITERS; ++i) {
        f32x4 rf, ru;
        quant4(r[i], mu, is, &rf, &ru);
        __builtin_nontemporal_store(rf, of + (LDS_ITERS + i) * THREADS + t);
        __builtin_nontemporal_store(ru, ou + (LDS_ITERS + i) * THREADS + t);
    }
}

// ---------------- fallback (round-3 proven path) ----------------
#define RB_PER 16
#define RBLOCKS (NSAMP * RB_PER)
#define RTHREADS 256
#define RVEC (SELEMS / RB_PER / 4)
#define N2THREADS 512

__global__ __launch_bounds__(RTHREADS)
void gn_reduce(const float* __restrict__ x, double* __restrict__ part) {
    int blk = blockIdx.x;
    int samp = blk >> 4;
    int sub  = blk & 15;
    const f32x4* xs = reinterpret_cast<const f32x4*>(x)
                    + (size_t)samp * (SELEMS / 4) + (size_t)sub * RVEC;
    double s = 0.0, s2 = 0.0;
    for (int i = threadIdx.x; i < RVEC; i += RTHREADS) {
        f32x4 v = xs[i];
        double a = v.x, b = v.y, c = v.z, d = v.w;
        s  += (a + b) + (c + d);
        s2 += (a * a + b * b) + (c * c + d * d);
    }
    __shared__ double sh1[RTHREADS];
    __shared__ double sh2[RTHREADS];
    int tid = threadIdx.x;
    sh1[tid] = s; sh2[tid] = s2;
    __syncthreads();
    for (int off = RTHREADS / 2; off > 0; off >>= 1) {
        if (tid < off) { sh1[tid] += sh1[tid + off]; sh2[tid] += sh2[tid + off]; }
        __syncthreads();
    }
    if (tid == 0) { part[blk * 2] = sh1[0]; part[blk * 2 + 1] = sh2[0]; }
}

__global__ __launch_bounds__(N2THREADS)
void gn_norm(const float* __restrict__ x, const double* __restrict__ part,
             const int* __restrict__ lut,
             float* __restrict__ outf, float* __restrict__ outu) {
    int blk  = blockIdx.x;
    int samp = blk >> 4;
    int sub  = blk & 15;
    float mu, is;
    compute_params(part, lut, samp, RB_PER, &mu, &is);
    size_t base = (size_t)samp * (SELEMS / 4) + (size_t)sub * RVEC;
    const f32x4* xs = reinterpret_cast<const f32x4*>(x) + base;
    f32x4* of = reinterpret_cast<f32x4*>(outf) + base;
    f32x4* ou = reinterpret_cast<f32x4*>(outu) + base;
    for (int i = RVEC - N2THREADS + (int)threadIdx.x; i >= 0; i -= N2THREADS) {
        f32x4 v = xs[i];
        f32x4 rf, ru;
        quant4(v, mu, is, &rf, &ru);
        __builtin_nontemporal_store(rf, of + i);
        __builtin_nontemporal_store(ru, ou + i);
    }
}

extern "C" void kernel_launch(void* const* d_in, const int* in_sizes, int n_in,
                              void* d_out, int out_size, void* d_ws, size_t ws_size,
                              hipStream_t stream) {
    const float* x = (const float*)d_in[0];
    const int* lut = (const int*)d_in[1];
    float* outf = (float*)d_out;
    float* outu = outf + (size_t)NSAMP * SELEMS;
    double* part = (double*)d_ws;   // fused: 4096 pairs = 64 KB

    void* args[] = { (void*)&x, (void*)&part, (void*)&lut,
                     (void*)&outf, (void*)&outu };
    hipError_t e = hipLaunchCooperativeKernel((const void*)gn_fused,
                                              dim3(BLOCKS), dim3(THREADS),
                                              args, 0, stream);
    if (e != hipSuccess) {
        // cooperative launch unsupported here (e.g. under graph capture):
        // proven two-kernel fallback, same math.
        gn_reduce<<<RBLOCKS, RTHREADS, 0, stream>>>(x, part);
        gn_norm<<<RBLOCKS, N2THREADS, 0, stream>>>(x, part, lut, outf, outu);
    }
}

// Round 6
// 130.299 us; speedup vs baseline: 1.0904x; 1.0904x over previous
//
#include <hip/hip_runtime.h>
#include <hip/hip_cooperative_groups.h>
#include <math.h>

// GroupNorm2dInteger fused, partial on-chip retention.
// 512 blocks x 512 threads. Per thread 32 float4 (128 elems):
//   9 iters retained in LDS (72 KB/block), 12 iters in regs (48 VGPR),
//   11 iters NOT retained (re-read from HBM in phase B).
// Register arithmetic (round-5 lesson): 2 blk/CU retention = 9*16KB LDS
// + 12*4B*512thr*2blk = 147KB LDS + 192KB VGPR of 512KB -> ~95 VGPR/wave
// incl. working set, under the 128 cap of __launch_bounds__(512,4).
// Sync: per-sample flags (memset to 0 each launch), agent-scope atomics;
// cooperative launch used ONLY to validate co-residency. Fallback: the
// proven two-kernel path.

#define NSAMP 64
#define SELEMS (128 * 64 * 64)          // 524288 per sample
#define BLOCKS 512
#define THREADS 512
#define BPS 8                           // blocks per sample
#define CHUNK4 (SELEMS / BPS / 4)       // 16384 float4 per block
#define LDSI 9
#define REGI 12
#define SKIPI 11                        // re-read in phase B
// LDSI + REGI + SKIPI == CHUNK4 / THREADS == 32

typedef float f32x4 __attribute__((ext_vector_type(4)));

struct QPair { float f, u; };

__device__ __forceinline__ QPair quant1(float v, float mu, float is) {
    float d = (v - mu) * is;
    float t = floorf(d * 16.0f);
    t = fminf(fmaxf(t, -128.0f), 127.0f);
    QPair q;
    q.f = t * 0.0625f;
    q.u = (float)(((int)t) & 255);
    return q;
}

__device__ __forceinline__ void quant4(f32x4 v, float mu, float is,
                                       f32x4* rf, f32x4* ru) {
    QPair a = quant1(v.x, mu, is);
    QPair b = quant1(v.y, mu, is);
    QPair c = quant1(v.z, mu, is);
    QPair d = quant1(v.w, mu, is);
    f32x4 f, u;
    f.x = a.f; f.y = b.f; f.z = c.f; f.w = d.f;
    u.x = a.u; u.y = b.u; u.z = c.u; u.w = d.u;
    *rf = f; *ru = u;
}

// Shared finalize math (from summed sum/sum2). Integer isqrt is exact.
__device__ __forceinline__ void finalize_params(double sum, double sum2,
                                                const int* __restrict__ lut,
                                                float* mu_out, float* is_out) {
    const double invN = 1.0 / (double)SELEMS;
    double mean = sum * invN;
    double mi = floor(mean * 16.0);                 // integer_floor_quantizer(mu,8,4)
    mi = fmin(fmax(mi, -128.0), 127.0);
    double mu = mi / 16.0;
    double var = sum2 * invN - 2.0 * mu * mean + mu * mu;
    if (var < 0.0) var = 0.0;
    double vq = floor(var * 256.0);                 // integer_floor_quantizer(var,16,8)
    vq = fmin(fmax(vq, -32768.0), 32767.0);
    int var_int = (int)vq;

    int res;
    if (var_int <= 0) {
        res = 65535;
    } else {
        int msb = 31 - __clz(var_int);      // <= 14
        int x_red = var_int << (15 - msb);  // MSB at bit 15
        int idx = (x_red >> 10) & 31;       // top 5 frac bits
        int lv = lut[idx];
        int e = 24 - msb;                   // in [10, 24]
        int e2 = e >> 1;
        if (e & 1) lv = (lv * 46340) >> 15; // SQRT2_FIX
        res = lv >> (15 - e2);              // shift in [3,10], never negative
        if (res > 65535) res = 65535;
    }
    if (res > 32767) res = 32767;           // quantize(res/256,16,8) clip

    *mu_out = (float)mu;
    *is_out = (float)res * (1.0f / 256.0f);
}

__global__ __launch_bounds__(THREADS, 4)
void gn_fused(const float* __restrict__ x, double* __restrict__ part,
              int* __restrict__ cnt, const int* __restrict__ lut,
              float* __restrict__ outf, float* __restrict__ outu) {
    int blk  = blockIdx.x;
    int samp = blk >> 3;
    int t    = threadIdx.x;
    size_t base4 = (size_t)blk * CHUNK4;
    const f32x4* xs = reinterpret_cast<const f32x4*>(x) + base4;

    __shared__ f32x4 lds4[LDSI * THREADS];   // 72 KB
    __shared__ double wsum[8][2];
    __shared__ float psh[2];

    f32x4 r[REGI];
    double s = 0.0, s2 = 0.0;

    #pragma unroll
    for (int i = 0; i < LDSI; ++i) {
        f32x4 v = xs[i * THREADS + t];
        lds4[i * THREADS + t] = v;
        double a = v.x, b = v.y, c = v.z, d = v.w;
        s  += (a + b) + (c + d);
        s2 += (a * a + b * b) + (c * c + d * d);
    }
    #pragma unroll
    for (int i = 0; i < REGI; ++i) {
        f32x4 v = xs[(LDSI + i) * THREADS + t];
        r[i] = v;
        double a = v.x, b = v.y, c = v.z, d = v.w;
        s  += (a + b) + (c + d);
        s2 += (a * a + b * b) + (c * c + d * d);
    }
    #pragma unroll
    for (int i = 0; i < SKIPI; ++i) {
        f32x4 v = xs[(LDSI + REGI + i) * THREADS + t];
        double a = v.x, b = v.y, c = v.z, d = v.w;
        s  += (a + b) + (c + d);
        s2 += (a * a + b * b) + (c * c + d * d);
    }

    // wave (64-lane) shuffle reduction, deterministic
    #pragma unroll
    for (int off = 32; off > 0; off >>= 1) {
        s  += __shfl_down(s,  off, 64);
        s2 += __shfl_down(s2, off, 64);
    }
    int wid = t >> 6, lane = t & 63;
    if (lane == 0) { wsum[wid][0] = s; wsum[wid][1] = s2; }
    __syncthreads();

    if (t == 0) {
        // block partial in fixed order
        double bs = 0.0, bs2 = 0.0;
        #pragma unroll
        for (int j = 0; j < 8; ++j) { bs += wsum[j][0]; bs2 += wsum[j][1]; }
        __hip_atomic_store(&part[blk * 2],     bs,  __ATOMIC_RELAXED, __HIP_MEMORY_SCOPE_AGENT);
        __hip_atomic_store(&part[blk * 2 + 1], bs2, __ATOMIC_RELAXED, __HIP_MEMORY_SCOPE_AGENT);
        __threadfence();
        atomicAdd(&cnt[samp], 1);        // device-scope release of this block's pair
        // wait for the sample's 8 blocks
        while (__hip_atomic_load(&cnt[samp], __ATOMIC_ACQUIRE, __HIP_MEMORY_SCOPE_AGENT) < BPS) {
            __builtin_amdgcn_s_sleep(1);
        }
        // finalize in fixed order -> bit-identical in all 8 blocks
        double sum = 0.0, sum2 = 0.0;
        #pragma unroll
        for (int j = 0; j < BPS; ++j) {
            sum  += __hip_atomic_load(&part[(samp * BPS + j) * 2],     __ATOMIC_RELAXED, __HIP_MEMORY_SCOPE_AGENT);
            sum2 += __hip_atomic_load(&part[(samp * BPS + j) * 2 + 1], __ATOMIC_RELAXED, __HIP_MEMORY_SCOPE_AGENT);
        }
        float mu, is;
        finalize_params(sum, sum2, lut, &mu, &is);
        psh[0] = mu; psh[1] = is;
    }
    __syncthreads();
    float mu = psh[0], is = psh[1];

    f32x4* of = reinterpret_cast<f32x4*>(outf) + base4;
    f32x4* ou = reinterpret_cast<f32x4*>(outu) + base4;

    #pragma unroll
    for (int i = 0; i < LDSI; ++i) {
        f32x4 v = lds4[i * THREADS + t];
        f32x4 rf, ru;
        quant4(v, mu, is, &rf, &ru);
        __builtin_nontemporal_store(rf, of + i * THREADS + t);
        __builtin_nontemporal_store(ru, ou + i * THREADS + t);
    }
    #pragma unroll
    for (int i = 0; i < REGI; ++i) {
        f32x4 rf, ru;
        quant4(r[i], mu, is, &rf, &ru);
        __builtin_nontemporal_store(rf, of + (LDSI + i) * THREADS + t);
        __builtin_nontemporal_store(ru, ou + (LDSI + i) * THREADS + t);
    }
    #pragma unroll
    for (int i = 0; i < SKIPI; ++i) {
        f32x4 v = xs[(LDSI + REGI + i) * THREADS + t];   // re-read
        f32x4 rf, ru;
        quant4(v, mu, is, &rf, &ru);
        __builtin_nontemporal_store(rf, of + (LDSI + REGI + i) * THREADS + t);
        __builtin_nontemporal_store(ru, ou + (LDSI + REGI + i) * THREADS + t);
    }
}

// ---------------- fallback (round-3 proven path) ----------------
#define RB_PER 16
#define RBLOCKS (NSAMP * RB_PER)
#define RTHREADS 256
#define RVEC (SELEMS / RB_PER / 4)
#define N2THREADS 512

__global__ __launch_bounds__(RTHREADS)
void gn_reduce(const float* __restrict__ x, double* __restrict__ part) {
    int blk = blockIdx.x;
    int samp = blk >> 4;
    int sub  = blk & 15;
    const f32x4* xs = reinterpret_cast<const f32x4*>(x)
                    + (size_t)samp * (SELEMS / 4) + (size_t)sub * RVEC;
    double s = 0.0, s2 = 0.0;
    for (int i = threadIdx.x; i < RVEC; i += RTHREADS) {
        f32x4 v = xs[i];
        double a = v.x, b = v.y, c = v.z, d = v.w;
        s  += (a + b) + (c + d);
        s2 += (a * a + b * b) + (c * c + d * d);
    }
    __shared__ double sh1[RTHREADS];
    __shared__ double sh2[RTHREADS];
    int tid = threadIdx.x;
    sh1[tid] = s; sh2[tid] = s2;
    __syncthreads();
    for (int off = RTHREADS / 2; off > 0; off >>= 1) {
        if (tid < off) { sh1[tid] += sh1[tid + off]; sh2[tid] += sh2[tid + off]; }
        __syncthreads();
    }
    if (tid == 0) { part[blk * 2] = sh1[0]; part[blk * 2 + 1] = sh2[0]; }
}

__global__ __launch_bounds__(N2THREADS)
void gn_norm(const float* __restrict__ x, const double* __restrict__ part,
             const int* __restrict__ lut,
             float* __restrict__ outf, float* __restrict__ outu) {
    int blk  = blockIdx.x;
    int samp = blk >> 4;
    int sub  = blk & 15;
    double sum = 0.0, sum2 = 0.0;
    #pragma unroll
    for (int j = 0; j < RB_PER; ++j) {
        sum  += part[(samp * RB_PER + j) * 2];
        sum2 += part[(samp * RB_PER + j) * 2 + 1];
    }
    float mu, is;
    finalize_params(sum, sum2, lut, &mu, &is);
    size_t base = (size_t)samp * (SELEMS / 4) + (size_t)sub * RVEC;
    const f32x4* xs = reinterpret_cast<const f32x4*>(x) + base;
    f32x4* of = reinterpret_cast<f32x4*>(outf) + base;
    f32x4* ou = reinterpret_cast<f32x4*>(outu) + base;
    for (int i = RVEC - N2THREADS + (int)threadIdx.x; i >= 0; i -= N2THREADS) {
        f32x4 v = xs[i];
        f32x4 rf, ru;
        quant4(v, mu, is, &rf, &ru);
        __builtin_nontemporal_store(rf, of + i);
        __builtin_nontemporal_store(ru, ou + i);
    }
}

extern "C" void kernel_launch(void* const* d_in, const int* in_sizes, int n_in,
                              void* d_out, int out_size, void* d_ws, size_t ws_size,
                              hipStream_t stream) {
    const float* x = (const float*)d_in[0];
    const int* lut = (const int*)d_in[1];
    float* outf = (float*)d_out;
    float* outu = outf + (size_t)NSAMP * SELEMS;
    double* part = (double*)d_ws;                       // 1024 pairs max = 16 KB
    int* cnt = (int*)((char*)d_ws + 16384);             // 64 flags

    // zero the per-sample flags every launch (replay-safe)
    hipMemsetAsync(cnt, 0, NSAMP * sizeof(int), stream);

    void* args[] = { (void*)&x, (void*)&part, (void*)&cnt, (void*)&lut,
                     (void*)&outf, (void*)&outu };
    hipError_t e = hipLaunchCooperativeKernel((const void*)gn_fused,
                                              dim3(BLOCKS), dim3(THREADS),
                                              args, 0, stream);
    if (e != hipSuccess) {
        // co-residency not validated: proven two-kernel fallback, same math.
        gn_reduce<<<RBLOCKS, RTHREADS, 0, stream>>>(x, part);
        gn_norm<<<RBLOCKS, N2THREADS, 0, stream>>>(x, part, lut, outf, outu);
    }
}

// Round 7
// 112.817 us; speedup vs baseline: 1.2593x; 1.1550x over previous
//
#include <hip/hip_runtime.h>
#include <math.h>

// GroupNorm2dInteger fused, partial on-chip retention, NO cooperative launch.
// 512 blocks x 512 threads. Co-residency by construction: LDS 72.3KB -> 2 blk/CU,
// __launch_bounds__(512,4) caps VGPR at 128 -> >=2 blk/CU; 256 CU * 2 = 512 slots
// so all 512 blocks are resident => per-sample flag spin cannot deadlock.
// Per thread 32 float4 (128 elems): 9 iters retained in LDS, 8 in regs (32 VGPR,
// far under the cap - round-5 spill lesson), 15 re-read from HBM in phase B.
// Traffic: 134 read + 63 re-read + 268 write = 465 MB (vs 536 two-kernel).
// Sync: per-sample counter in d_ws, zeroed each launch by a 1-block micro-kernel
// (no hipMemsetAsync - round-6 showed fill+coop graph nodes cost ~150us).

#define NSAMP 64
#define SELEMS (128 * 64 * 64)          // 524288 per sample
#define BLOCKS 512
#define THREADS 512
#define BPS 8                           // blocks per sample
#define CHUNK4 (SELEMS / BPS / 4)       // 16384 float4 per block
#define LDSI 9                          // 9*512 float4 = 72 KB LDS
#define REGI 8                          // 8 float4 = 32 VGPRs
#define SKIPI 15                        // re-read in phase B
// LDSI + REGI + SKIPI == CHUNK4 / THREADS == 32

typedef float f32x4 __attribute__((ext_vector_type(4)));

struct QPair { float f, u; };

__device__ __forceinline__ QPair quant1(float v, float mu, float is) {
    float d = (v - mu) * is;
    float t = floorf(d * 16.0f);
    t = fminf(fmaxf(t, -128.0f), 127.0f);
    QPair q;
    q.f = t * 0.0625f;
    q.u = (float)(((int)t) & 255);
    return q;
}

__device__ __forceinline__ void quant4(f32x4 v, float mu, float is,
                                       f32x4* rf, f32x4* ru) {
    QPair a = quant1(v.x, mu, is);
    QPair b = quant1(v.y, mu, is);
    QPair c = quant1(v.z, mu, is);
    QPair d = quant1(v.w, mu, is);
    f32x4 f, u;
    f.x = a.f; f.y = b.f; f.z = c.f; f.w = d.f;
    u.x = a.u; u.y = b.u; u.z = c.u; u.w = d.u;
    *rf = f; *ru = u;
}

// Finalize math from summed sum/sum2. Integer isqrt is exact; fixed order ->
// bit-identical params in every block of a sample.
__device__ __forceinline__ void finalize_params(double sum, double sum2,
                                                const int* __restrict__ lut,
                                                float* mu_out, float* is_out) {
    const double invN = 1.0 / (double)SELEMS;
    double mean = sum * invN;
    double mi = floor(mean * 16.0);                 // integer_floor_quantizer(mu,8,4)
    mi = fmin(fmax(mi, -128.0), 127.0);
    double mu = mi / 16.0;
    double var = sum2 * invN - 2.0 * mu * mean + mu * mu;
    if (var < 0.0) var = 0.0;
    double vq = floor(var * 256.0);                 // integer_floor_quantizer(var,16,8)
    vq = fmin(fmax(vq, -32768.0), 32767.0);
    int var_int = (int)vq;

    int res;
    if (var_int <= 0) {
        res = 65535;
    } else {
        int msb = 31 - __clz(var_int);      // <= 14
        int x_red = var_int << (15 - msb);  // MSB at bit 15
        int idx = (x_red >> 10) & 31;       // top 5 frac bits
        int lv = lut[idx];
        int e = 24 - msb;                   // in [10, 24]
        int e2 = e >> 1;
        if (e & 1) lv = (lv * 46340) >> 15; // SQRT2_FIX
        res = lv >> (15 - e2);              // shift in [3,10], never negative
        if (res > 65535) res = 65535;
    }
    if (res > 32767) res = 32767;           // quantize(res/256,16,8) clip

    *mu_out = (float)mu;
    *is_out = (float)res * (1.0f / 256.0f);
}

__global__ void gn_zero_flags(int* __restrict__ cnt) {
    cnt[threadIdx.x] = 0;
}

__global__ __launch_bounds__(THREADS, 4)
void gn_fused(const float* __restrict__ x, double* __restrict__ part,
              int* __restrict__ cnt, const int* __restrict__ lut,
              float* __restrict__ outf, float* __restrict__ outu) {
    int blk  = blockIdx.x;
    int samp = blk >> 3;
    int t    = threadIdx.x;
    size_t base4 = (size_t)blk * CHUNK4;
    const f32x4* xs = reinterpret_cast<const f32x4*>(x) + base4;

    __shared__ f32x4 lds4[LDSI * THREADS];   // 72 KB
    __shared__ double wsum[8][2];
    __shared__ float psh[2];

    f32x4 r[REGI];
    double s = 0.0, s2 = 0.0;

    #pragma unroll
    for (int i = 0; i < LDSI; ++i) {
        f32x4 v = xs[i * THREADS + t];
        lds4[i * THREADS + t] = v;
        double a = v.x, b = v.y, c = v.z, d = v.w;
        s  += (a + b) + (c + d);
        s2 += (a * a + b * b) + (c * c + d * d);
    }
    #pragma unroll
    for (int i = 0; i < REGI; ++i) {
        f32x4 v = xs[(LDSI + i) * THREADS + t];
        r[i] = v;
        double a = v.x, b = v.y, c = v.z, d = v.w;
        s  += (a + b) + (c + d);
        s2 += (a * a + b * b) + (c * c + d * d);
    }
    #pragma unroll 5
    for (int i = 0; i < SKIPI; ++i) {
        f32x4 v = xs[(LDSI + REGI + i) * THREADS + t];
        double a = v.x, b = v.y, c = v.z, d = v.w;
        s  += (a + b) + (c + d);
        s2 += (a * a + b * b) + (c * c + d * d);
    }

    // wave (64-lane) shuffle reduction, deterministic
    #pragma unroll
    for (int off = 32; off > 0; off >>= 1) {
        s  += __shfl_down(s,  off, 64);
        s2 += __shfl_down(s2, off, 64);
    }
    int wid = t >> 6, lane = t & 63;
    if (lane == 0) { wsum[wid][0] = s; wsum[wid][1] = s2; }
    __syncthreads();

    if (t == 0) {
        double bs = 0.0, bs2 = 0.0;
        #pragma unroll
        for (int j = 0; j < 8; ++j) { bs += wsum[j][0]; bs2 += wsum[j][1]; }
        __hip_atomic_store(&part[blk * 2],     bs,  __ATOMIC_RELAXED, __HIP_MEMORY_SCOPE_AGENT);
        __hip_atomic_store(&part[blk * 2 + 1], bs2, __ATOMIC_RELAXED, __HIP_MEMORY_SCOPE_AGENT);
        __threadfence();                 // release the pair
        atomicAdd(&cnt[samp], 1);        // device-scope
        while (__hip_atomic_load(&cnt[samp], __ATOMIC_ACQUIRE, __HIP_MEMORY_SCOPE_AGENT) < BPS) {
            __builtin_amdgcn_s_sleep(1);
        }
        double sum = 0.0, sum2 = 0.0;
        #pragma unroll
        for (int j = 0; j < BPS; ++j) {
            sum  += __hip_atomic_load(&part[(samp * BPS + j) * 2],     __ATOMIC_RELAXED, __HIP_MEMORY_SCOPE_AGENT);
            sum2 += __hip_atomic_load(&part[(samp * BPS + j) * 2 + 1], __ATOMIC_RELAXED, __HIP_MEMORY_SCOPE_AGENT);
        }
        float mu, is;
        finalize_params(sum, sum2, lut, &mu, &is);
        psh[0] = mu; psh[1] = is;
    }
    __syncthreads();
    float mu = psh[0], is = psh[1];

    f32x4* of = reinterpret_cast<f32x4*>(outf) + base4;
    f32x4* ou = reinterpret_cast<f32x4*>(outu) + base4;

    #pragma unroll
    for (int i = 0; i < LDSI; ++i) {
        f32x4 v = lds4[i * THREADS + t];
        f32x4 rf, ru;
        quant4(v, mu, is, &rf, &ru);
        __builtin_nontemporal_store(rf, of + i * THREADS + t);
        __builtin_nontemporal_store(ru, ou + i * THREADS + t);
    }
    #pragma unroll
    for (int i = 0; i < REGI; ++i) {
        f32x4 rf, ru;
        quant4(r[i], mu, is, &rf, &ru);
        __builtin_nontemporal_store(rf, of + (LDSI + i) * THREADS + t);
        __builtin_nontemporal_store(ru, ou + (LDSI + i) * THREADS + t);
    }
    #pragma unroll 5
    for (int i = 0; i < SKIPI; ++i) {
        f32x4 v = xs[(LDSI + REGI + i) * THREADS + t];   // re-read 15/32
        f32x4 rf, ru;
        quant4(v, mu, is, &rf, &ru);
        __builtin_nontemporal_store(rf, of + (LDSI + REGI + i) * THREADS + t);
        __builtin_nontemporal_store(ru, ou + (LDSI + REGI + i) * THREADS + t);
    }
}

extern "C" void kernel_launch(void* const* d_in, const int* in_sizes, int n_in,
                              void* d_out, int out_size, void* d_ws, size_t ws_size,
                              hipStream_t stream) {
    const float* x = (const float*)d_in[0];
    const int* lut = (const int*)d_in[1];
    float* outf = (float*)d_out;
    float* outu = outf + (size_t)NSAMP * SELEMS;
    double* part = (double*)d_ws;                       // 512 pairs = 8 KB
    int* cnt = (int*)((char*)d_ws + 16384);             // 64 flags

    gn_zero_flags<<<1, NSAMP, 0, stream>>>(cnt);
    gn_fused<<<BLOCKS, THREADS, 0, stream>>>(x, part, cnt, lut, outf, outu);
}

// Round 8
// 83.881 us; speedup vs baseline: 1.6937x; 1.3450x over previous
//
#include <hip/hip_runtime.h>
#include <math.h>

// GroupNorm2dInteger: x (64,128,64,64) f32, per-sample integer-quantized groupnorm.
// ROUND-3 PROVEN STRUCTURE (83.7 us, absmax 0) — reverted to after fused/retention
// attempts (rounds 4-7) all regressed: retention competes for the VGPR/LDS the
// streaming loop needs, and its 13% traffic saving was eaten by >=30% overhead.
// Pass 1: per-sample partial sum/sumsq (f64, deterministic tree reduce), 16 blocks/sample.
// Pass 2: same chunk decomposition, traversed in REVERSE (descending 8KB groups) so the
//         freshest-in-L3 lines from pass 1 are consumed first. Each block redundantly
//         finalizes its sample's stats (fixed f64 order -> bit-identical params).
// Effective 6.4 TB/s on 536 MB = 94% of measured fill-rate ceiling -> memory roofline.

#define NSAMP 64
#define SELEMS (128 * 64 * 64)          // 524288 per sample
#define RB_PER 16                       // chunks per sample
#define RBLOCKS (NSAMP * RB_PER)        // 1024
#define RTHREADS 256
#define RVEC (SELEMS / RB_PER / 4)      // 8192 float4 per chunk

#define N2THREADS 512

typedef float f32x4 __attribute__((ext_vector_type(4)));

__global__ __launch_bounds__(RTHREADS)
void gn_reduce(const float* __restrict__ x, double* __restrict__ part) {
    int blk = blockIdx.x;
    int samp = blk >> 4;          // / RB_PER
    int sub  = blk & 15;
    const f32x4* xs = reinterpret_cast<const f32x4*>(x)
                    + (size_t)samp * (SELEMS / 4)
                    + (size_t)sub * RVEC;
    double s = 0.0, s2 = 0.0;
    for (int i = threadIdx.x; i < RVEC; i += RTHREADS) {
        f32x4 v = xs[i];
        double a = v.x, b = v.y, c = v.z, d = v.w;
        s  += (a + b) + (c + d);
        s2 += (a * a + b * b) + (c * c + d * d);
    }
    __shared__ double sh1[RTHREADS];
    __shared__ double sh2[RTHREADS];
    int tid = threadIdx.x;
    sh1[tid] = s; sh2[tid] = s2;
    __syncthreads();
    for (int off = RTHREADS / 2; off > 0; off >>= 1) {
        if (tid < off) { sh1[tid] += sh1[tid + off]; sh2[tid] += sh2[tid + off]; }
        __syncthreads();
    }
    if (tid == 0) { part[blk * 2] = sh1[0]; part[blk * 2 + 1] = sh2[0]; }
}

// Redundant per-block finalize: identical f64 summation order in every block of a
// sample -> bit-identical mu / inv_sqrt everywhere. Integer isqrt is exact.
__device__ __forceinline__ void compute_params(const double* __restrict__ part,
                                               const int* __restrict__ lut,
                                               int samp, float* mu_out, float* is_out) {
    double sum = 0.0, sum2 = 0.0;
    #pragma unroll
    for (int i = 0; i < RB_PER; ++i) {
        sum  += part[(samp * RB_PER + i) * 2];
        sum2 += part[(samp * RB_PER + i) * 2 + 1];
    }
    const double invN = 1.0 / (double)SELEMS;
    double mean = sum * invN;
    double mi = floor(mean * 16.0);                 // integer_floor_quantizer(mu,8,4)
    mi = fmin(fmax(mi, -128.0), 127.0);
    double mu = mi / 16.0;
    double var = sum2 * invN - 2.0 * mu * mean + mu * mu;
    if (var < 0.0) var = 0.0;
    double vq = floor(var * 256.0);                 // integer_floor_quantizer(var,16,8)
    vq = fmin(fmax(vq, -32768.0), 32767.0);
    int var_int = (int)vq;

    int res;
    if (var_int <= 0) {
        res = 65535;
    } else {
        int msb = 31 - __clz(var_int);      // <= 14
        int x_red = var_int << (15 - msb);  // MSB at bit 15
        int idx = (x_red >> 10) & 31;       // top 5 frac bits
        int lv = lut[idx];
        int e = 24 - msb;                   // in [10, 24]
        int e2 = e >> 1;
        if (e & 1) lv = (lv * 46340) >> 15; // SQRT2_FIX
        res = lv >> (15 - e2);              // shift in [3,10], never negative
        if (res > 65535) res = 65535;
    }
    if (res > 32767) res = 32767;           // quantize(res/256, 16, 8) clip

    *mu_out = (float)mu;
    *is_out = (float)res * (1.0f / 256.0f);
}

__global__ __launch_bounds__(N2THREADS)
void gn_norm(const float* __restrict__ x, const double* __restrict__ part,
             const int* __restrict__ lut,
             float* __restrict__ outf, float* __restrict__ outu) {
    int blk  = blockIdx.x;        // 0..1023, same chunk map as gn_reduce
    int samp = blk >> 4;
    int sub  = blk & 15;

    float mu, is;
    compute_params(part, lut, samp, &mu, &is);

    size_t base = (size_t)samp * (SELEMS / 4) + (size_t)sub * RVEC;
    const f32x4* xs = reinterpret_cast<const f32x4*>(x) + base;
    f32x4* of = reinterpret_cast<f32x4*>(outf) + base;
    f32x4* ou = reinterpret_cast<f32x4*>(outu) + base;

    // Reverse traversal: descending 8KB groups (freshest L3 lines first),
    // forward/coalesced within each group.
    for (int i = RVEC - N2THREADS + (int)threadIdx.x; i >= 0; i -= N2THREADS) {
        f32x4 v = xs[i];
        f32x4 rf, ru;
        {
            float d = (v.x - mu) * is;
            float t = floorf(d * 16.0f);
            t = fminf(fmaxf(t, -128.0f), 127.0f);
            rf.x = t * 0.0625f;
            ru.x = (float)(((int)t) & 255);
        }
        {
            float d = (v.y - mu) * is;
            float t = floorf(d * 16.0f);
            t = fminf(fmaxf(t, -128.0f), 127.0f);
            rf.y = t * 0.0625f;
            ru.y = (float)(((int)t) & 255);
        }
        {
            float d = (v.z - mu) * is;
            float t = floorf(d * 16.0f);
            t = fminf(fmaxf(t, -128.0f), 127.0f);
            rf.z = t * 0.0625f;
            ru.z = (float)(((int)t) & 255);
        }
        {
            float d = (v.w - mu) * is;
            float t = floorf(d * 16.0f);
            t = fminf(fmaxf(t, -128.0f), 127.0f);
            rf.w = t * 0.0625f;
            ru.w = (float)(((int)t) & 255);
        }
        __builtin_nontemporal_store(rf, of + i);
        __builtin_nontemporal_store(ru, ou + i);
    }
}

extern "C" void kernel_launch(void* const* d_in, const int* in_sizes, int n_in,
                              void* d_out, int out_size, void* d_ws, size_t ws_size,
                              hipStream_t stream) {
    const float* x = (const float*)d_in[0];
    const int* lut = (const int*)d_in[1];
    float* outf = (float*)d_out;
    float* outu = outf + (size_t)NSAMP * SELEMS;
    double* part = (double*)d_ws;   // RBLOCKS*2 doubles = 16 KiB

    gn_reduce<<<RBLOCKS, RTHREADS, 0, stream>>>(x, part);
    gn_norm<<<RBLOCKS, N2THREADS, 0, stream>>>(x, part, lut, outf, outu);
}